// Round 3
// baseline (1001.798 us; speedup 1.0000x reference)
//
#include <hip/hip_runtime.h>
#include <math.h>

// Problem constants (from reference)
#define NN 2048   // nodes
#define CC 128    // channels
#define DD 9      // irreps dim
#define SS 50     // species
// chunks: (mul, ir, icat_offset)
#define MUL0 7
#define IR0  1
#define MUL1 11
#define IR1  3
#define MUL2 12
#define IR2  5

constexpr int CH = 2;                 // channels per block
constexpr int NITEM = 729;            // 81*(1+3+5) output positions per (n,c)
constexpr int BLK = 256;

// ---------------- pre-kernel: bucket nodes by species ----------------
__global__ __launch_bounds__(256)
void build_lists_kernel(const int* __restrict__ index,
                        int* __restrict__ offsets,   // SS+1 ints
                        int* __restrict__ nodelist)  // NN ints
{
    __shared__ int h[SS];
    __shared__ int base[SS + 1];
    const int t = threadIdx.x;
    if (t < SS) h[t] = 0;
    __syncthreads();
    for (int n = t; n < NN; n += blockDim.x) atomicAdd(&h[index[n]], 1);
    __syncthreads();
    if (t == 0) {
        int acc = 0;
        for (int s = 0; s < SS; ++s) { base[s] = acc; acc += h[s]; }
        base[SS] = acc;
    }
    __syncthreads();
    if (t < SS) h[t] = base[t];   // running cursor
    __syncthreads();
    for (int n = t; n < NN; n += blockDim.x) {
        int pos = atomicAdd(&h[index[n]], 1);
        nodelist[pos] = n;
    }
    if (t <= SS) offsets[t] = base[t];
}

// ---------------- per-thread T fragment: T[c][j] = sum_k u[ab,j,k,i]*wv[k][c] ----------------
template <int MUL, int IR>
__device__ __forceinline__ void computeT(const float* __restrict__ u, int ab, int i,
                                         const float* __restrict__ wv /* LDS [MUL][CH] */,
                                         float T[CH][DD])
{
    float wr[MUL][CH];
#pragma unroll
    for (int k = 0; k < MUL; ++k)
#pragma unroll
        for (int c = 0; c < CH; ++c) wr[k][c] = wv[k * CH + c];

    const float* ub = u + (size_t)ab * (DD * MUL * IR) + i;
#pragma unroll
    for (int j = 0; j < DD; ++j) {
        float acc[CH];
#pragma unroll
        for (int c = 0; c < CH; ++c) acc[c] = 0.f;
#pragma unroll
        for (int k = 0; k < MUL; ++k) {
            float uv = ub[(j * MUL + k) * IR];
#pragma unroll
            for (int c = 0; c < CH; ++c) acc[c] += uv * wr[k][c];
        }
#pragma unroll
        for (int c = 0; c < CH; ++c) T[c][j] = acc[c];
    }
}

// ---------------- main kernel: block = (species, channel-pair) ----------------
__global__ __launch_bounds__(BLK)
void contract_kernel(const float* __restrict__ x,
                     const float* __restrict__ u0, const float* __restrict__ w0,
                     const float* __restrict__ u1, const float* __restrict__ w1,
                     const float* __restrict__ u2, const float* __restrict__ w2,
                     const int* __restrict__ offsets, const int* __restrict__ nodelist,
                     float* __restrict__ out,
                     float sc0, float sc1, float sc2)
{
    const int t   = threadIdx.x;
    const int blk = blockIdx.x;
    const int s   = blk / (CC / CH);
    const int cb  = (blk % (CC / CH)) * CH;
    const int o0 = offsets[s], o1 = offsets[s + 1];
    if (o0 == o1) return;   // no nodes of this species

    // stage w[s,:,cb..cb+CH) * scale into LDS, layout [k][c]
    __shared__ float wv0[MUL0 * CH], wv1[MUL1 * CH], wv2[MUL2 * CH];
    if (t < MUL0 * CH) {
        int k = t / CH, c = t % CH;
        wv0[t] = w0[((size_t)s * MUL0 + k) * CC + cb + c] * sc0;
    } else if (t < (MUL0 + MUL1) * CH) {
        int q = t - MUL0 * CH; int k = q / CH, c = q % CH;
        wv1[q] = w1[((size_t)s * MUL1 + k) * CC + cb + c] * sc1;
    } else if (t < (MUL0 + MUL1 + MUL2) * CH) {
        int q = t - (MUL0 + MUL1) * CH; int k = q / CH, c = q % CH;
        wv2[q] = w2[((size_t)s * MUL2 + k) * CC + cb + c] * sc2;
    }
    __syncthreads();

    // T fragments, chunk-major item order so waves are chunk-uniform:
    // items [0,81): chunk0; [81,324): chunk1 (ab*3+i); [324,729): chunk2 (ab*5+i)
    float T[3][CH][DD];
    int outp[3];
#pragma unroll
    for (int p3 = 0; p3 < 3; ++p3) {
        int m = t + BLK * p3;
        if (m >= NITEM) { outp[p3] = -1; continue; }
        if (m < 81) {
            computeT<MUL0, IR0>(u0, m, 0, wv0, T[p3]);
            outp[p3] = m * 9 + 0;
        } else if (m < 324) {
            int e = m - 81; int ab = e / 3; int i = e - ab * 3;
            computeT<MUL1, IR1>(u1, ab, i, wv1, T[p3]);
            outp[p3] = ab * 9 + 1 + i;
        } else {
            int e = m - 324; int ab = e / 5; int i = e - ab * 5;
            computeT<MUL2, IR2>(u2, ab, i, wv2, T[p3]);
            outp[p3] = ab * 9 + 4 + i;
        }
    }

    // apply to every node of this species
    for (int idx = o0; idx < o1; ++idx) {
        const int n = nodelist[idx];
        const float* xb = x + ((size_t)n * CC + cb) * DD;
        float xv[CH][DD];
#pragma unroll
        for (int c = 0; c < CH; ++c)
#pragma unroll
            for (int j = 0; j < DD; ++j) xv[c][j] = xb[c * DD + j];

        float* ob = out + ((size_t)n * CC + cb) * NITEM;
#pragma unroll
        for (int p3 = 0; p3 < 3; ++p3) {
            if (outp[p3] < 0) continue;
#pragma unroll
            for (int c = 0; c < CH; ++c) {
                float acc = 0.f;
#pragma unroll
                for (int j = 0; j < DD; ++j) acc += xv[c][j] * T[p3][c][j];
                ob[c * NITEM + outp[p3]] = acc;
            }
        }
    }
}

extern "C" void kernel_launch(void* const* d_in, const int* in_sizes, int n_in,
                              void* d_out, int out_size, void* d_ws, size_t ws_size,
                              hipStream_t stream)
{
    // setup_inputs dict order: node_feats, index, u0, w0, u1, w1, u2, w2
    const float* x   = (const float*)d_in[0];
    const int*   idx = (const int*)  d_in[1];
    const float* u0  = (const float*)d_in[2];
    const float* w0  = (const float*)d_in[3];
    const float* u1  = (const float*)d_in[4];
    const float* w1  = (const float*)d_in[5];
    const float* u2  = (const float*)d_in[6];
    const float* w2  = (const float*)d_in[7];
    float* out = (float*)d_out;

    int* offsets  = (int*)d_ws;       // SS+1 ints (padded to 64)
    int* nodelist = offsets + 64;     // NN ints

    build_lists_kernel<<<1, 256, 0, stream>>>(idx, offsets, nodelist);

    const float sc0 = powf((float)MUL0, -0.25f);
    const float sc1 = powf((float)MUL1, -0.25f);
    const float sc2 = powf((float)MUL2, -0.25f);

    contract_kernel<<<SS * (CC / CH), BLK, 0, stream>>>(
        x, u0, w0, u1, w1, u2, w2, offsets, nodelist, out, sc0, sc1, sc2);
}